// Round 1
// baseline (4541.403 us; speedup 1.0000x reference)
//
#include <hip/hip_runtime.h>

#define HD 256
#define ID 32
#define OD 10
#define BATCH 256
#define SEQ 512
#define NWG 16
#define BB 16
#define HPAD 264   // padded h row stride in bf16 elems (breaks 512B bank alias)

typedef __attribute__((ext_vector_type(4))) float f32x4;
typedef __attribute__((ext_vector_type(8))) unsigned short u16x8;
typedef __attribute__((ext_vector_type(8))) __bf16 bf16x8;

static __device__ __forceinline__ unsigned short f2bf(float f) {
  unsigned u = __builtin_bit_cast(unsigned, f);
  u += 0x7fffu + ((u >> 16) & 1u);          // round-to-nearest-even
  return (unsigned short)(u >> 16);
}
static __device__ __forceinline__ float bf2f(unsigned short s) {
  unsigned u = ((unsigned)s) << 16;
  return __builtin_bit_cast(float, u);
}
static __device__ __forceinline__ f32x4 mfma16(u16x8 a, u16x8 b, f32x4 c) {
  return __builtin_amdgcn_mfma_f32_16x16x32_bf16(
      __builtin_bit_cast(bf16x8, a), __builtin_bit_cast(bf16x8, b), c, 0, 0, 0);
}
static __device__ __forceinline__ float fast_sigmoid(float x) {
  return 1.f / (1.f + __expf(-x));
}
static __device__ __forceinline__ float fast_tanh(float x) {
  return 1.f - 2.f / (__expf(2.f * x) + 1.f);
}

// ---------------------------------------------------------------------------
// Kernel 1: pack [Wx;Wh] (K=288 x N=1024, bf16) into B-fragment-major layout.
// Frag f = w*72 + cs*9 + kt   (w=wave 0..7, cs=gate*2+u 0..7, kt=k-tile 0..8)
// Within frag: lane l, slot i -> element B[k = 32*kt + 8*(l>>4) + i]
//                                       [col = gate*256 + 32*w + 16*u + (l&15)]
// stored contiguously: offset = f*512 + l*8 (ushort units) -> coalesced 1KB frag
// ---------------------------------------------------------------------------
__global__ void pack_w(const float* __restrict__ Wgx, const float* __restrict__ Wgh,
                       const float* __restrict__ Wix, const float* __restrict__ Wih,
                       const float* __restrict__ Wfx, const float* __restrict__ Wfh,
                       const float* __restrict__ Wox, const float* __restrict__ Woh,
                       unsigned short* __restrict__ Wpk) {
  int p = blockIdx.x * blockDim.x + threadIdx.x;
  if (p >= 576 * 64) return;
  int f = p >> 6, l = p & 63;
  int w = f / 72, rem = f % 72;
  int cs = rem / 9, kt = rem % 9;
  int g = cs >> 1, u = cs & 1;
  int j = 32 * w + 16 * u + (l & 15);
  const float* Wx[4] = {Wgx, Wix, Wfx, Wox};
  const float* Wh[4] = {Wgh, Wih, Wfh, Woh};
  u16x8 v;
  #pragma unroll
  for (int i = 0; i < 8; ++i) {
    int k = kt * 32 + 8 * (l >> 4) + i;
    float val = (k < ID) ? Wx[g][k * HD + j] : Wh[g][(k - ID) * HD + j];
    v[i] = f2bf(val);
  }
  *(u16x8*)(Wpk + ((size_t)f << 9) + (l << 3)) = v;
}

// ---------------------------------------------------------------------------
// Kernel 2: persistent recurrent kernel. 16 WGs x 512 threads (8 waves).
// WG b0 owns batch rows [b0, b0+16). Wave w owns j-slice [32w, 32w+32)
// across all 4 gates (8 col-tiles). Streams packed B-frags from L2 each step.
// ---------------------------------------------------------------------------
__global__ void __launch_bounds__(512) lstm_rec(
    const float* __restrict__ x, const unsigned short* __restrict__ Wpk,
    const float* __restrict__ bgp, const float* __restrict__ bip,
    const float* __restrict__ bfp, const float* __restrict__ bop,
    const float* __restrict__ Wph, const float* __restrict__ bpp,
    float* __restrict__ out) {
  __shared__ __align__(16) unsigned short h_lds[BB * HPAD];  // bf16 h state
  __shared__ float logits[BB][OD];
  int tid = threadIdx.x;
  int w = tid >> 6, l = tid & 63;
  int l15 = l & 15, l4 = l >> 4;
  int b0 = blockIdx.x * BB;

  for (int idx = tid; idx < BB * HPAD; idx += 512) h_lds[idx] = 0;

  float bias[8];
  {
    const float* bsrc[4] = {bgp, bip, bfp, bop};
    #pragma unroll
    for (int cs = 0; cs < 8; ++cs)
      bias[cs] = bsrc[cs >> 1][32 * w + 16 * (cs & 1) + l15];
  }
  f32x4 cst[2];
  cst[0] = f32x4{0.f, 0.f, 0.f, 0.f};
  cst[1] = f32x4{0.f, 0.f, 0.f, 0.f};

  const unsigned short* wp = Wpk + ((size_t)(w * 72) << 9) + (l << 3);
  const float* xrow = x + ((size_t)(b0 + l15) * SEQ) * ID + 8 * l4;

  __syncthreads();

  for (int t = 0; t < SEQ; ++t) {
    // ---- A fragments: [x_t | h_{t-1}], lane holds row l15, k-slots (l4,i) ----
    u16x8 a[9];
    {
      const float* xp = xrow + (size_t)t * ID;
      float4 v0 = *(const float4*)xp;
      float4 v1 = *(const float4*)(xp + 4);
      a[0][0] = f2bf(v0.x); a[0][1] = f2bf(v0.y); a[0][2] = f2bf(v0.z); a[0][3] = f2bf(v0.w);
      a[0][4] = f2bf(v1.x); a[0][5] = f2bf(v1.y); a[0][6] = f2bf(v1.z); a[0][7] = f2bf(v1.w);
    }
    #pragma unroll
    for (int kt = 1; kt < 9; ++kt)
      a[kt] = *(const u16x8*)&h_lds[l15 * HPAD + (kt - 1) * 32 + 8 * l4];

    __syncthreads();  // everyone done reading h_{t-1} before it is overwritten

    // ---- stream B-frags (double-buffered) + MFMA ----
    u16x8 buf[2][9];
    #pragma unroll
    for (int kt = 0; kt < 9; ++kt)
      buf[0][kt] = *(const u16x8*)(wp + ((size_t)kt << 9));
    f32x4 acc[8];
    #pragma unroll
    for (int cs = 0; cs < 8; ++cs) {
      if (cs < 7) {
        #pragma unroll
        for (int kt = 0; kt < 9; ++kt)
          buf[(cs + 1) & 1][kt] =
              *(const u16x8*)(wp + ((size_t)((cs + 1) * 9 + kt) << 9));
      }
      f32x4 v = f32x4{0.f, 0.f, 0.f, 0.f};
      #pragma unroll
      for (int kt = 0; kt < 9; ++kt) v = mfma16(a[kt], buf[cs & 1][kt], v);
      acc[cs] = v;
    }

    // ---- gates: per-lane; D layout col=l15 (j), rows 4*l4+i (batch) ----
    #pragma unroll
    for (int u = 0; u < 2; ++u) {
      #pragma unroll
      for (int i = 0; i < 4; ++i) {
        float zg = acc[0 + u][i] + bias[0 + u];
        float zi = acc[2 + u][i] + bias[2 + u];
        float zf = acc[4 + u][i] + bias[4 + u];
        float zo = acc[6 + u][i] + bias[6 + u];
        float gg = fast_tanh(zg);
        float ii = fast_sigmoid(zi);
        float ff = fast_sigmoid(zf);
        float oo = fast_sigmoid(zo);
        float cc = gg * ii + cst[u][i] * ff;
        cst[u][i] = cc;
        float hh = fast_tanh(cc) * oo;
        h_lds[(4 * l4 + i) * HPAD + 32 * w + 16 * u + l15] = f2bf(hh);
      }
    }
    __syncthreads();  // h_t complete for next step
  }

  // ---- epilogue: out = softmax(h @ Wph + bp) ----
  if (tid < BB * OD) {
    int b = tid / OD, j = tid - b * OD;
    float s = bpp[j];
    for (int k = 0; k < HD; ++k)
      s += bf2f(h_lds[b * HPAD + k]) * Wph[k * OD + j];
    logits[b][j] = s;
  }
  __syncthreads();
  if (tid < BB) {
    float m = -1e30f;
    #pragma unroll
    for (int j = 0; j < OD; ++j) m = fmaxf(m, logits[tid][j]);
    float e[OD], sum = 0.f;
    #pragma unroll
    for (int j = 0; j < OD; ++j) { e[j] = __expf(logits[tid][j] - m); sum += e[j]; }
    float inv = 1.f / sum;
    #pragma unroll
    for (int j = 0; j < OD; ++j) out[(b0 + tid) * OD + j] = e[j] * inv;
  }
}

extern "C" void kernel_launch(void* const* d_in, const int* in_sizes, int n_in,
                              void* d_out, int out_size, void* d_ws, size_t ws_size,
                              hipStream_t stream) {
  const float* X   = (const float*)d_in[0];
  const float* Wgx = (const float*)d_in[1];
  const float* Wgh = (const float*)d_in[2];
  const float* bg  = (const float*)d_in[3];
  const float* Wix = (const float*)d_in[4];
  const float* Wih = (const float*)d_in[5];
  const float* bi  = (const float*)d_in[6];
  const float* Wfx = (const float*)d_in[7];
  const float* Wfh = (const float*)d_in[8];
  const float* bf  = (const float*)d_in[9];
  const float* Wox = (const float*)d_in[10];
  const float* Woh = (const float*)d_in[11];
  const float* bo  = (const float*)d_in[12];
  const float* Wph = (const float*)d_in[13];
  const float* bp  = (const float*)d_in[14];
  unsigned short* Wpk = (unsigned short*)d_ws;  // 576 KB packed weights

  pack_w<<<dim3(72), dim3(512), 0, stream>>>(Wgx, Wgh, Wix, Wih, Wfx, Wfh,
                                             Wox, Woh, Wpk);
  lstm_rec<<<dim3(NWG), dim3(512), 0, stream>>>(X, Wpk, bg, bi, bf, bo,
                                                Wph, bp, (float*)d_out);
}

// Round 2
// 4050.510 us; speedup vs baseline: 1.1212x; 1.1212x over previous
//
#include <hip/hip_runtime.h>

#define HD 256
#define ID 32
#define OD 10
#define SEQ 512
#define NWG 16
#define BB 16
#define NWAVE 4
#define NREG 92            // register-resident frags per wave
#define NLDS 37            // LDS-resident frags per wave
#define SMEM_BYTES (8192 + NWAVE * NLDS * 1024)   // 159744 B < 160 KiB

typedef __attribute__((ext_vector_type(4))) float f32x4;
typedef __attribute__((ext_vector_type(8))) unsigned short u16x8;
typedef __attribute__((ext_vector_type(8))) __bf16 bf16x8;

static __device__ __forceinline__ unsigned short f2bf(float f) {
  unsigned u = __builtin_bit_cast(unsigned, f);
  u += 0x7fffu + ((u >> 16) & 1u);          // RNE
  return (unsigned short)(u >> 16);
}
static __device__ __forceinline__ float bf2f(unsigned short s) {
  unsigned u = ((unsigned)s) << 16;
  return __builtin_bit_cast(float, u);
}
static __device__ __forceinline__ f32x4 mfma16(u16x8 a, u16x8 b, f32x4 c) {
  return __builtin_amdgcn_mfma_f32_16x16x32_bf16(
      __builtin_bit_cast(bf16x8, a), __builtin_bit_cast(bf16x8, b), c, 0, 0, 0);
}
static __device__ __forceinline__ float fast_sigmoid(float x) {
  return 1.f / (1.f + __expf(-x));
}
static __device__ __forceinline__ float fast_tanh(float x) {
  return 1.f - 2.f / (__expf(2.f * x) + 1.f);
}

// ---------------------------------------------------------------------------
// Pack [Wx;Wh] (K=288 x N=1024 bf16) into fragment-major order.
// Global frag id f = w*144 + lfid, lfid = ph*36 + g*9 + kt
//   w  = wave 0..3  (owns j-cols [64w, 64w+64))
//   ph = phase 0..3 (j-sub-block of 16)
//   g  = gate 0..3  (g,i,f,o)
//   kt = k-tile 0..8 (K=288)
// Within frag: lane l, slot i -> B[k = 32*kt + 8*(l>>4) + i][j = 64w+16ph+(l&15)]
// stored at Wpk[f*512 + l*8] (ushorts) -> contiguous 1KB per frag.
// ---------------------------------------------------------------------------
__global__ void pack_w(const float* __restrict__ Wgx, const float* __restrict__ Wgh,
                       const float* __restrict__ Wix, const float* __restrict__ Wih,
                       const float* __restrict__ Wfx, const float* __restrict__ Wfh,
                       const float* __restrict__ Wox, const float* __restrict__ Woh,
                       unsigned short* __restrict__ Wpk) {
  int p = blockIdx.x * blockDim.x + threadIdx.x;
  if (p >= 576 * 64) return;
  int f = p >> 6, l = p & 63;
  int w = f / 144, r = f % 144;
  int ph = r / 36, r2 = r % 36;
  int g = r2 / 9, kt = r2 % 9;
  int j = 64 * w + 16 * ph + (l & 15);
  const float* Wx[4] = {Wgx, Wix, Wfx, Wox};
  const float* Wh[4] = {Wgh, Wih, Wfh, Woh};
  u16x8 v;
  #pragma unroll
  for (int i = 0; i < 8; ++i) {
    int k = kt * 32 + 8 * (l >> 4) + i;
    float val = (k < ID) ? Wx[g][k * HD + j] : Wh[g][(k - ID) * HD + j];
    v[i] = f2bf(val);
  }
  *(u16x8*)(Wpk + ((size_t)f << 9) + (l << 3)) = v;
}

// ---------------------------------------------------------------------------
// Persistent recurrent kernel: 16 WGs x 256 threads (4 waves, 1/SIMD, 512 VGPR).
// Weights: 92 frags/wave in VGPRs, 37 in LDS, 15 streamed from L2 per step.
// h state (16 x 256 bf16) in LDS with chunk-XOR swizzle (conflict-free b128).
// ---------------------------------------------------------------------------
__global__ void __launch_bounds__(256, 1) lstm_rec(
    const float* __restrict__ x, const unsigned short* __restrict__ Wpk,
    const float* __restrict__ bgp, const float* __restrict__ bip,
    const float* __restrict__ bfp, const float* __restrict__ bop,
    const float* __restrict__ Wph, const float* __restrict__ bpp,
    float* __restrict__ out) {
  extern __shared__ __align__(16) unsigned char smem[];
  unsigned short* hbuf = (unsigned short*)smem;            // 16 x 256 bf16, swizzled
  unsigned short* wlds = (unsigned short*)(smem + 8192);   // NWAVE*NLDS KB

  int tid = threadIdx.x;
  int w = tid >> 6, l = tid & 63;
  int l15 = l & 15, l4 = l >> 4;
  int b0 = blockIdx.x * BB;

  const unsigned short* wbase = Wpk + (((size_t)w * 144) << 9);

  // ---- stage LDS-resident weight frags (once) ----
  for (int f = 0; f < NLDS; ++f) {
    u16x8 v = *(const u16x8*)(wbase + (((size_t)(NREG + f)) << 9) + (l << 3));
    *(u16x8*)(wlds + (((size_t)(w * NLDS + f)) << 9) + (l << 3)) = v;
  }
  // ---- zero h ----
  for (int idx = tid; idx < BB * HD; idx += 256) hbuf[idx] = 0;

  // ---- register-resident weight frags ----
  u16x8 wreg[NREG];
  #pragma unroll
  for (int lfid = 0; lfid < NREG; ++lfid)
    wreg[lfid] = *(const u16x8*)(wbase + (((size_t)lfid) << 9) + (l << 3));

  // ---- biases: bias[ph][g] for j = 64w + 16ph + l15 ----
  float bias[4][4];
  {
    const float* bsrc[4] = {bgp, bip, bfp, bop};
    #pragma unroll
    for (int ph = 0; ph < 4; ++ph)
      #pragma unroll
      for (int g = 0; g < 4; ++g)
        bias[ph][g] = bsrc[g][64 * w + 16 * ph + l15];
  }
  float cst[4][4];
  #pragma unroll
  for (int ph = 0; ph < 4; ++ph)
    #pragma unroll
    for (int i = 0; i < 4; ++i) cst[ph][i] = 0.f;

  const float* xrow = x + ((size_t)(b0 + l15) * SEQ) * ID + 8 * l4;
  float4 xv0 = *(const float4*)(xrow);
  float4 xv1 = *(const float4*)(xrow + 4);

  __syncthreads();

  for (int t = 0; t < SEQ; ++t) {
    // ---- A fragments: a[0] = x_t slice; a[1..8] = h_{t-1} (swizzled LDS) ----
    u16x8 a[9];
    a[0][0] = f2bf(xv0.x); a[0][1] = f2bf(xv0.y); a[0][2] = f2bf(xv0.z); a[0][3] = f2bf(xv0.w);
    a[0][4] = f2bf(xv1.x); a[0][5] = f2bf(xv1.y); a[0][6] = f2bf(xv1.z); a[0][7] = f2bf(xv1.w);
    {  // prefetch next x (lands well before next step)
      int tn = (t + 1 < SEQ) ? (t + 1) : t;
      xv0 = *(const float4*)(xrow + (size_t)tn * ID);
      xv1 = *(const float4*)(xrow + (size_t)tn * ID + 4);
    }
    #pragma unroll
    for (int kt = 1; kt < 9; ++kt) {
      int c = (kt - 1) * 4 + l4;
      int cs = c ^ (l15 & 7);
      a[kt] = *(const u16x8*)(hbuf + l15 * HD + cs * 8);
    }
    __syncthreads();  // all waves finished reading h_{t-1}

    // ---- L2 stream, round A: lfid 129..133 (g2 kt3..7 of phase 3) ----
    u16x8 buf[5];
    #pragma unroll
    for (int q = 0; q < 5; ++q)
      buf[q] = *(const u16x8*)(wbase + (((size_t)(129 + q)) << 9) + (l << 3));

    #pragma unroll
    for (int ph = 0; ph < 4; ++ph) {
      f32x4 acc[4];
      #pragma unroll
      for (int g = 0; g < 4; ++g) {
        float bb = bias[ph][g];
        acc[g] = f32x4{bb, bb, bb, bb};
      }

      if (ph < 3) {
        #pragma unroll
        for (int g = 0; g < 4; ++g)
          #pragma unroll
          for (int kt = 0; kt < 9; ++kt) {
            const int lfid = ph * 36 + g * 9 + kt;
            u16x8 bw;
            if (lfid < NREG) {
              bw = wreg[lfid];
            } else {
              bw = *(const u16x8*)(wlds +
                    (((size_t)(w * NLDS + (lfid - NREG))) << 9) + (l << 3));
            }
            acc[g] = mfma16(a[kt], bw, acc[g]);
          }
      } else {
        // phase 3: lfid 108..128 from LDS (idx 16..36), 129..143 from L2 stream
        // consume round A: g2 kt3..7
        #pragma unroll
        for (int q = 0; q < 5; ++q) acc[2] = mfma16(a[3 + q], buf[q], acc[2]);
        // issue round B: lfid 134..138 (g2 kt8, g3 kt0..3)
        #pragma unroll
        for (int q = 0; q < 5; ++q)
          buf[q] = *(const u16x8*)(wbase + (((size_t)(134 + q)) << 9) + (l << 3));
        // 11 LDS MFMAs: lfid 108..118 (g0 kt0..8, g1 kt0..1)
        #pragma unroll
        for (int m = 0; m < 11; ++m) {
          const int lfid = 108 + m;
          const int g = (lfid - 108) / 9, kt = (lfid - 108) % 9;
          u16x8 bw = *(const u16x8*)(wlds +
                    (((size_t)(w * NLDS + (lfid - NREG))) << 9) + (l << 3));
          acc[g] = mfma16(a[kt], bw, acc[g]);
        }
        // consume round B
        acc[2] = mfma16(a[8], buf[0], acc[2]);
        #pragma unroll
        for (int q = 1; q < 5; ++q) acc[3] = mfma16(a[q - 1], buf[q], acc[3]);
        // issue round C: lfid 139..143 (g3 kt4..8)
        #pragma unroll
        for (int q = 0; q < 5; ++q)
          buf[q] = *(const u16x8*)(wbase + (((size_t)(139 + q)) << 9) + (l << 3));
        // 10 LDS MFMAs: lfid 119..128 (g1 kt2..8, g2 kt0..2)
        #pragma unroll
        for (int m = 0; m < 10; ++m) {
          const int lfid = 119 + m;
          const int g = (lfid - 108) / 9, kt = (lfid - 108) % 9;
          u16x8 bw = *(const u16x8*)(wlds +
                    (((size_t)(w * NLDS + (lfid - NREG))) << 9) + (l << 3));
          acc[g] = mfma16(a[kt], bw, acc[g]);
        }
        // consume round C: g3 kt4..8
        #pragma unroll
        for (int q = 0; q < 5; ++q) acc[3] = mfma16(a[4 + q], buf[q], acc[3]);
      }

      // ---- gates for this phase's 16 cols; D layout: col=l15, row=4*l4+i ----
      #pragma unroll
      for (int i = 0; i < 4; ++i) {
        float gg = fast_tanh(acc[0][i]);
        float ii = fast_sigmoid(acc[1][i]);
        float ff = fast_sigmoid(acc[2][i]);
        float oo = fast_sigmoid(acc[3][i]);
        float cc = gg * ii + cst[ph][i] * ff;
        cst[ph][i] = cc;
        float hh = fast_tanh(cc) * oo;
        int row = 4 * l4 + i;
        int col = 64 * w + 16 * ph + l15;
        int ch = (col >> 3) ^ (row & 7);
        hbuf[row * HD + ch * 8 + (col & 7)] = f2bf(hh);
      }
    }
    __syncthreads();  // h_t complete
  }

  // ---- epilogue: logits = h @ Wph + bp, then softmax ----
  float logit = 0.f;
  int eb = tid & 15, ej = tid >> 4;   // 160 active threads: (batch, out-col)
  if (tid < 16 * OD) {
    float s = bpp[ej];
    for (int k = 0; k < HD; ++k) {
      int ch = (k >> 3) ^ (eb & 7);
      s += bf2f(hbuf[eb * HD + ch * 8 + (k & 7)]) * Wph[k * OD + ej];
    }
    logit = s;
  }
  __syncthreads();                     // all h reads done
  float* lbuf = (float*)smem;          // reuse h region for logits
  if (tid < 16 * OD) lbuf[eb * OD + ej] = logit;
  __syncthreads();
  if (tid < BB) {
    float m = -1e30f;
    #pragma unroll
    for (int j = 0; j < OD; ++j) m = fmaxf(m, lbuf[tid * OD + j]);
    float e[OD], sum = 0.f;
    #pragma unroll
    for (int j = 0; j < OD; ++j) { e[j] = __expf(lbuf[tid * OD + j] - m); sum += e[j]; }
    float inv = 1.f / sum;
    #pragma unroll
    for (int j = 0; j < OD; ++j) out[(b0 + tid) * OD + j] = e[j] * inv;
  }
}

extern "C" void kernel_launch(void* const* d_in, const int* in_sizes, int n_in,
                              void* d_out, int out_size, void* d_ws, size_t ws_size,
                              hipStream_t stream) {
  const float* X   = (const float*)d_in[0];
  const float* Wgx = (const float*)d_in[1];
  const float* Wgh = (const float*)d_in[2];
  const float* bg  = (const float*)d_in[3];
  const float* Wix = (const float*)d_in[4];
  const float* Wih = (const float*)d_in[5];
  const float* bi  = (const float*)d_in[6];
  const float* Wfx = (const float*)d_in[7];
  const float* Wfh = (const float*)d_in[8];
  const float* bf  = (const float*)d_in[9];
  const float* Wox = (const float*)d_in[10];
  const float* Woh = (const float*)d_in[11];
  const float* bo  = (const float*)d_in[12];
  const float* Wph = (const float*)d_in[13];
  const float* bp  = (const float*)d_in[14];
  unsigned short* Wpk = (unsigned short*)d_ws;  // 576 KB packed weights

  (void)hipFuncSetAttribute((const void*)lstm_rec,
                            hipFuncAttributeMaxDynamicSharedMemorySize,
                            SMEM_BYTES);

  pack_w<<<dim3(72), dim3(512), 0, stream>>>(Wgx, Wgh, Wix, Wih, Wfx, Wfh,
                                             Wox, Woh, Wpk);
  lstm_rec<<<dim3(NWG), dim3(256), SMEM_BYTES, stream>>>(
      X, Wpk, bg, bi, bf, bo, Wph, bp, (float*)d_out);
}